// Round 1
// baseline (77.236 us; speedup 1.0000x reference)
//
#include <hip/hip_runtime.h>
#include <math.h>

// Batched FK chain: re = T1..T25; out = concat(points = re[:3,3], vectors = re[:3,2]).
// All constant matrices are +/-90 or 180 deg rotations + translations -> signed
// permutes + adds. Propagate p (w=1) and v (w=0) right-to-left through the chain.

#define DEGf 0.017453292519943295f

__device__ __forceinline__ void rotz(float& x, float& y, float c, float s) {
    float nx = c * x - s * y;
    float ny = s * x + c * y;
    x = nx; y = ny;
}

__global__ __launch_bounds__(256) void fk_kernel(const float* __restrict__ thetas,
                                                 float* __restrict__ out,
                                                 int B) {
    __shared__ float sth[256 * 7];
    const int tid = threadIdx.x;
    const long long blockBase = (long long)blockIdx.x * 256;
    const long long gbase = blockBase * 7;
    const long long total = (long long)B * 7;

#pragma unroll
    for (int j = 0; j < 7; ++j) {
        long long idx = gbase + (long long)j * 256 + tid;
        if (idx < total) sth[j * 256 + tid] = thetas[idx];
    }
    __syncthreads();

    const long long i = blockBase + tid;
    if (i >= B) return;

    float th[7];
#pragma unroll
    for (int j = 0; j < 7; ++j) th[j] = sth[tid * 7 + j];

    // Angles in radians (signs/scales folded from the reference chain)
    const float a0 = th[0] * DEGf;
    const float a1 = th[1] * DEGf;
    const float a2 = -th[2] * DEGf;
    const float a3 = -th[3] * DEGf;
    const float a4 = th[4] * (-0.5f * DEGf);
    const float a5 = (th[5] * (1.0f / 4.5f) + 10.0f) * DEGf;
    const float a6 = (20.0f + (th[6] + 180.0f) * (1.0f / 4.5f)) * DEGf;

    float s0, c0, s1, c1, s2, c2, s3, c3, s4, c4, s5, c5, s6, c6;
    __sincosf(a0, &s0, &c0);
    __sincosf(a1, &s1, &c1);
    __sincosf(a2, &s2, &c2);
    __sincosf(a3, &s3, &c3);
    __sincosf(a4, &s4, &c4);
    __sincosf(a5, &s5, &c5);
    __sincosf(a6, &s6, &c6);

    // After T25=Ry(90): p = col3 = (0,0,0); v = col2 = (1,0,0).
    // T24 = Txyz(6,0,0): p.x += 6
    float px = 6.0f, py = 0.0f, pz = 0.0f;
    float vx = 1.0f, vy = 0.0f, vz = 0.0f;
    float t;

    // T23 = Rz(a6)
    rotz(px, py, c6, s6);
    rotz(vx, vy, c6, s6);
    // T22 = Txyz(6,0,0); T21 = Txyz(0,-1,0)
    px += 6.0f; py -= 1.0f;
    // T20 = Rz(a5)
    rotz(px, py, c5, s5);
    rotz(vx, vy, c5, s5);
    // T19 = Rz(-90): (x,y) -> (y,-x)
    t = px; px = py; py = -t;
    t = vx; vx = vy; vy = -t;
    // T18 = Rx(-90): (y,z) -> (z,-y)
    t = py; py = pz; pz = -t;
    t = vy; vy = vz; vz = -t;
    // T17 = Txyz(0,0,10)
    pz += 10.0f;
    // T16 = Rz(a4)
    rotz(px, py, c4, s4);
    rotz(vx, vy, c4, s4);
    // T15 = Ry(90): (x,z) -> (z,-x)
    t = px; px = pz; pz = -t;
    t = vx; vx = vz; vz = -t;
    // T14 = Txyz(10,0,0)
    px += 10.0f;
    // T13 = Rz(a3)
    rotz(px, py, c3, s3);
    rotz(vx, vy, c3, s3);
    // T12 = Rz(180): x=-x, y=-y
    px = -px; py = -py;
    vx = -vx; vy = -vy;
    // T11 = Rx(90): (y,z) -> (-z,y)
    t = py; py = -pz; pz = t;
    t = vy; vy = -vz; vz = t;
    // T10 = Txyz(17.5,0,0)
    px += 17.5f;
    // T9 = Rz(a2)
    rotz(px, py, c2, s2);
    rotz(vx, vy, c2, s2);
    // T8 = Rx(-90): (y,z) -> (z,-y)
    t = py; py = pz; pz = -t;
    t = vy; vy = vz; vz = -t;
    // T7 = Txyz(3,0,9.5)
    px += 3.0f; pz += 9.5f;
    // T6 = Rz(a1)
    rotz(px, py, c1, s1);
    rotz(vx, vy, c1, s1);
    // T5 = Ry(90): (x,z) -> (z,-x)
    t = px; px = pz; pz = -t;
    t = vx; vx = vz; vz = -t;
    // T4 = Txyz(0,-1.5,2.5)
    py -= 1.5f; pz += 2.5f;
    // T3 = Rz(a0)
    rotz(px, py, c0, s0);
    rotz(vx, vy, c0, s0);
    // T2 = Rz(90): (x,y) -> (-y,x)
    t = px; px = -py; py = t;
    t = vx; vx = -vy; vy = t;
    // T1 = Txyz(0,5,19.5)
    py += 5.0f; pz += 19.5f;

    // points at [0, 3B), vectors at [3B, 6B)
    float* po = out + 3ll * i;
    po[0] = px; po[1] = py; po[2] = pz;
    float* vo = out + 3ll * (long long)B + 3ll * i;
    vo[0] = vx; vo[1] = vy; vo[2] = vz;
}

extern "C" void kernel_launch(void* const* d_in, const int* in_sizes, int n_in,
                              void* d_out, int out_size, void* d_ws, size_t ws_size,
                              hipStream_t stream) {
    const float* thetas = (const float*)d_in[0];
    float* out = (float*)d_out;
    const int B = in_sizes[0] / 7;
    const int block = 256;
    const int grid = (B + block - 1) / block;
    fk_kernel<<<grid, block, 0, stream>>>(thetas, out, B);
}

// Round 2
// 76.314 us; speedup vs baseline: 1.0121x; 1.0121x over previous
//
#include <hip/hip_runtime.h>
#include <math.h>

// Batched FK chain: re = T1..T25; out = concat(points = re[:3,3], vectors = re[:3,2]).
// Constant matrices are signed permutes + translations; propagate p (w=1) and
// v (w=0) right-to-left. Fully float4-vectorized I/O via LDS staging:
//   in:  7 floats/item -> 448 float4 per 256-item block (coalesced)
//   out: 2x3 floats/item -> 2x192 float4 per block (coalesced)
// LDS readback strides are odd (7, 3) -> <=2-way bank aliasing = free (G4/m136).

#define DEGf 0.017453292519943295f

__device__ __forceinline__ void rotz(float& x, float& y, float c, float s) {
    float nx = c * x - s * y;
    float ny = s * x + c * y;
    x = nx; y = ny;
}

__global__ __launch_bounds__(256) void fk_kernel(const float* __restrict__ thetas,
                                                 float* __restrict__ out,
                                                 int B) {
    __shared__ float sbuf[7 * 256];
    float4* s4 = (float4*)sbuf;
    const int tid = threadIdx.x;
    const long long blockBase = (long long)blockIdx.x * 256;
    const bool full = (blockBase + 256 <= (long long)B) && ((B & 3) == 0);

    float th[7];
    if (full) {
        // 448 float4 = 1792 floats staged per block, fully coalesced
        const float4* t4 = (const float4*)(thetas + blockBase * 7);
        s4[tid] = t4[tid];
        if (tid < 192) s4[256 + tid] = t4[256 + tid];
        __syncthreads();
#pragma unroll
        for (int j = 0; j < 7; ++j) th[j] = sbuf[tid * 7 + j];
    } else {
        const long long i = blockBase + tid;
        if (i >= B) return;
#pragma unroll
        for (int j = 0; j < 7; ++j) th[j] = thetas[i * 7 + j];
    }

    // Angles in radians (signs/scales folded from the reference chain)
    const float a0 = th[0] * DEGf;
    const float a1 = th[1] * DEGf;
    const float a2 = -th[2] * DEGf;
    const float a3 = -th[3] * DEGf;
    const float a4 = th[4] * (-0.5f * DEGf);
    const float a5 = (th[5] * (1.0f / 4.5f) + 10.0f) * DEGf;
    const float a6 = (20.0f + (th[6] + 180.0f) * (1.0f / 4.5f)) * DEGf;

    float s0, c0, s1, c1, s2, c2, s3, c3, s4v, c4, s5, c5, s6, c6;
    __sincosf(a0, &s0, &c0);
    __sincosf(a1, &s1, &c1);
    __sincosf(a2, &s2, &c2);
    __sincosf(a3, &s3, &c3);
    __sincosf(a4, &s4v, &c4);
    __sincosf(a5, &s5, &c5);
    __sincosf(a6, &s6, &c6);

    // After T25=Ry(90): p = col3 = (0,0,0); v = col2 = (1,0,0).
    float px = 6.0f, py = 0.0f, pz = 0.0f;   // T24: Txyz(6,0,0)
    float vx = 1.0f, vy = 0.0f, vz = 0.0f;
    float t;

    rotz(px, py, c6, s6); rotz(vx, vy, c6, s6);      // T23 = Rz(a6)
    px += 6.0f; py -= 1.0f;                          // T22, T21
    rotz(px, py, c5, s5); rotz(vx, vy, c5, s5);      // T20 = Rz(a5)
    t = px; px = py; py = -t;                        // T19 = Rz(-90)
    t = vx; vx = vy; vy = -t;
    t = py; py = pz; pz = -t;                        // T18 = Rx(-90)
    t = vy; vy = vz; vz = -t;
    pz += 10.0f;                                     // T17
    rotz(px, py, c4, s4v); rotz(vx, vy, c4, s4v);    // T16 = Rz(a4)
    t = px; px = pz; pz = -t;                        // T15 = Ry(90)
    t = vx; vx = vz; vz = -t;
    px += 10.0f;                                     // T14
    rotz(px, py, c3, s3); rotz(vx, vy, c3, s3);      // T13 = Rz(a3)
    px = -px; py = -py; vx = -vx; vy = -vy;          // T12 = Rz(180)
    t = py; py = -pz; pz = t;                        // T11 = Rx(90)
    t = vy; vy = -vz; vz = t;
    px += 17.5f;                                     // T10
    rotz(px, py, c2, s2); rotz(vx, vy, c2, s2);      // T9 = Rz(a2)
    t = py; py = pz; pz = -t;                        // T8 = Rx(-90)
    t = vy; vy = vz; vz = -t;
    px += 3.0f; pz += 9.5f;                          // T7
    rotz(px, py, c1, s1); rotz(vx, vy, c1, s1);      // T6 = Rz(a1)
    t = px; px = pz; pz = -t;                        // T5 = Ry(90)
    t = vx; vx = vz; vz = -t;
    py -= 1.5f; pz += 2.5f;                          // T4
    rotz(px, py, c0, s0); rotz(vx, vy, c0, s0);      // T3 = Rz(a0)
    t = px; px = -py; py = t;                        // T2 = Rz(90)
    t = vx; vx = -vy; vy = t;
    py += 5.0f; pz += 19.5f;                         // T1

    if (full) {
        __syncthreads();  // done reading input stage
        // stage: points in sbuf[0..768), vectors in sbuf[768..1536)
        sbuf[tid * 3 + 0] = px;
        sbuf[tid * 3 + 1] = py;
        sbuf[tid * 3 + 2] = pz;
        sbuf[768 + tid * 3 + 0] = vx;
        sbuf[768 + tid * 3 + 1] = vy;
        sbuf[768 + tid * 3 + 2] = vz;
        __syncthreads();
        float4* o4p = (float4*)(out + blockBase * 3);
        float4* o4v = (float4*)(out + (long long)B * 3 + blockBase * 3);
        if (tid < 192) {
            o4p[tid] = s4[tid];
            o4v[tid] = s4[192 + tid];
        }
    } else {
        const long long i = blockBase + tid;
        float* po = out + 3ll * i;
        po[0] = px; po[1] = py; po[2] = pz;
        float* vo = out + 3ll * (long long)B + 3ll * i;
        vo[0] = vx; vo[1] = vy; vo[2] = vz;
    }
}

extern "C" void kernel_launch(void* const* d_in, const int* in_sizes, int n_in,
                              void* d_out, int out_size, void* d_ws, size_t ws_size,
                              hipStream_t stream) {
    const float* thetas = (const float*)d_in[0];
    float* out = (float*)d_out;
    const int B = in_sizes[0] / 7;
    const int block = 256;
    const int grid = (B + block - 1) / block;
    fk_kernel<<<grid, block, 0, stream>>>(thetas, out, B);
}